// Round 10
// baseline (377.149 us; speedup 1.0000x reference)
//
#include <hip/hip_runtime.h>
#include <hip/hip_bf16.h>
#include <stdint.h>

#define NR 8192   // rows (N)
#define ND 1024   // feature dim (D)

typedef __attribute__((ext_vector_type(8))) short bf16x8;  // 8 bf16 = 4 VGPR
typedef __attribute__((ext_vector_type(4))) float f32x4;   // MFMA C/D
typedef __attribute__((ext_vector_type(4))) float fvec4;   // ext-vector float4 (nontemporal ok)
typedef __attribute__((ext_vector_type(8))) unsigned short u16x8;

static __device__ __forceinline__ uint16_t f2bf(float f) {
  union { __hip_bfloat16 h; uint16_t u; } cv;
  cv.h = __float2bfloat16(f);
  return cv.u;
}
static __device__ __forceinline__ float bf2f(uint16_t u) {
  union { uint32_t i; float f; } cv;
  cv.i = ((uint32_t)u) << 16;
  return cv.f;
}

// ---------------- kernel 1: row L2 norm -> normalized bf16 ----------------
__global__ void k_norm(const float* __restrict__ X, uint16_t* __restrict__ Xn) {
  const int row = blockIdx.x;
  const int t = threadIdx.x;                    // 256 threads, 4 floats each
  const float4 v = reinterpret_cast<const float4*>(X + (size_t)row * ND)[t];
  float ss = v.x * v.x + v.y * v.y + v.z * v.z + v.w * v.w;
#pragma unroll
  for (int m = 1; m < 64; m <<= 1) ss += __shfl_xor(ss, m, 64);
  __shared__ float sred[4];
  if ((t & 63) == 0) sred[t >> 6] = ss;
  __syncthreads();
  const float tot = sred[0] + sred[1] + sred[2] + sred[3];
  const float inv = 1.0f / fmaxf(sqrtf(tot), 1e-12f);
  ushort4 o;
  o.x = f2bf(v.x * inv); o.y = f2bf(v.y * inv);
  o.z = f2bf(v.z * inv); o.w = f2bf(v.w * inv);
  reinterpret_cast<ushort4*>(Xn + (size_t)row * ND)[t] = o;
}

// ------------- kernel 1b: feats [NR][ND] f32 -> featsT [ND][NR] bf16 -------------
__global__ void k_transpose(const float* __restrict__ X, uint16_t* __restrict__ XT) {
  __shared__ uint16_t tile[32][33];
  const int ntr = NR / 32;                     // 256 row-tiles
  const int bx = blockIdx.x % ntr;             // row-tile of X
  const int by = blockIdx.x / ntr;             // col(dim)-tile of X
  const int r0 = bx * 32, d0 = by * 32;
  const int t = threadIdx.x;                   // 256
  const int rr = t >> 3, cc = (t & 7) * 4;
  const float4 v = *reinterpret_cast<const float4*>(&X[(size_t)(r0 + rr) * ND + d0 + cc]);
  tile[cc + 0][rr] = f2bf(v.x);
  tile[cc + 1][rr] = f2bf(v.y);
  tile[cc + 2][rr] = f2bf(v.z);
  tile[cc + 3][rr] = f2bf(v.w);
  __syncthreads();
  ushort4 o;
  o.x = tile[rr][cc + 0]; o.y = tile[rr][cc + 1];
  o.z = tile[rr][cc + 2]; o.w = tile[rr][cc + 3];
  *reinterpret_cast<ushort4*>(&XT[(size_t)(d0 + rr) * NR + r0 + cc]) = o;
}

// ---------------- 16-MFMA quadrant cluster (M-half x N-half x K=64) ----------------
template <int MH, int NH>
static __device__ __forceinline__ void mfma16(f32x4 (&acc)[8][4],
                                              const bf16x8 (&a_)[4][2],
                                              const bf16x8 (&b_)[2][2]) {
  __builtin_amdgcn_s_setprio(1);
#pragma unroll
  for (int kk = 0; kk < 2; ++kk)
#pragma unroll
    for (int m4 = 0; m4 < 4; ++m4)
#pragma unroll
      for (int n2 = 0; n2 < 2; ++n2)
        acc[MH * 4 + m4][NH * 2 + n2] = __builtin_amdgcn_mfma_f32_16x16x32_bf16(
            a_[m4][kk], b_[n2][kk], acc[MH * 4 + m4][NH * 2 + n2], 0, 0, 0);
  __builtin_amdgcn_s_setprio(0);
}

#define BAR()    __builtin_amdgcn_s_barrier()
#define LGKM()   asm volatile("s_waitcnt lgkmcnt(0)" ::: "memory")
#define VMW4()   asm volatile("s_waitcnt vmcnt(4)" ::: "memory")
#define VMW0()   asm volatile("s_waitcnt vmcnt(0)" ::: "memory")
#define SCHED0() __builtin_amdgcn_sched_barrier(0)

// ---------------- 256x256 8-phase BT GEMM core ----------------
// C[m][n] = sum_k A[m][k]*B[n][k]
// LDS map (bytes): dbuf d in {0,1}: d*65536 ; A half h: +h*16384 ; B: +32768+h*16384
// half-tile = [128 rows][64 k] bf16, 128B rows, stored in 16B chunks (8/row).
// Quarter-wave bank swizzle (conflict-free, R8-verified): data chunk c of row r
// lives at LDS chunk c ^ (r&7); stage source col pre-swizzled (same involution).
// 8 phases / 2 K-tiles (m201 template): per phase {ds_read quadrant frags ;
// interleaved global_load_lds prefetch ; BAR ; lgkm(0) ; 16 MFMA (setprio) ; BAR}.
// vmcnt(4) ONLY at ph4/ph8 (counted, never 0 in steady state). Race audit:
// every restage is >=1 barrier after that region's last read; ph4's vmcnt(4)
// guarantees d1 fully landed before ph5; ph8's guarantees d0(t+2) before ph1.
// Tail iterations stage nothing; ph4 drains to vmcnt(0) for the last d1.B.
template <int EPI, int NKT>
static __device__ __forceinline__ void gemm8_core(
    char* sm,
    const uint16_t* __restrict__ A, int lda,
    const uint16_t* __restrict__ B, int ldb,
    int row0, int col0,
    float* __restrict__ C, int ldc,
    uint16_t* __restrict__ Eo, float* __restrict__ partials, int rb, int cb) {
  const int tid = threadIdx.x;
  const int wid = tid >> 6;
  const int lane = tid & 63;
  const int wr = wid >> 2;            // 0..1  (M wave)
  const int wc = wid & 3;             // 0..3  (N wave)
  const int flane = lane & 15;
  const int qw = lane >> 4;           // quarter-wave index -> k chunk base
  const int rkey = flane & 7;         // row&7 swizzle key
  const int rowb = flane * 128;

  // staging source geometry (inverse-swizzled global source, linear LDS dest)
  const int colb = (((tid & 7) ^ ((tid >> 3) & 7)) * 16);
  const int r0s = tid >> 3;           // row for load g0; g1 adds 64

  const char* const Abyte = (const char*)A + (size_t)row0 * lda * 2;
  const char* const Bbyte = (const char*)B + (size_t)col0 * ldb * 2;

  f32x4 acc[8][4] = {};
  bf16x8 a_[4][2], b_[2][2];

  // one stageH call = 2 global_load_lds instr per wave (one half-tile)
  auto stageH = [&](int d, int isB, int h, int t) {
    const char* gb = isB ? Bbyte : Abyte;
    const int ld2 = (isB ? ldb : lda) * 2;
    const char* g0 = gb + (size_t)(h * 128 + r0s) * ld2 + t * 128 + colb;
    const char* g1 = g0 + (size_t)64 * ld2;
    char* l0 = sm + d * 65536 + isB * 32768 + h * 16384 + (wid << 10);
    __builtin_amdgcn_global_load_lds((const __attribute__((address_space(1))) void*)g0,
                                     (__attribute__((address_space(3))) void*)l0, 16, 0, 0);
    __builtin_amdgcn_global_load_lds((const __attribute__((address_space(1))) void*)g1,
                                     (__attribute__((address_space(3))) void*)(l0 + 8192), 16, 0, 0);
  };
  auto rdA = [&](int d, int mhalf) {        // 8 ds_read_b128
#pragma unroll
    for (int m4 = 0; m4 < 4; ++m4)
#pragma unroll
      for (int kk = 0; kk < 2; ++kk) {
        const int chunk = (qw + kk * 4) ^ rkey;
        a_[m4][kk] = *(const bf16x8*)(sm + d * 65536 + wr * 16384 +
                                      (mhalf * 4 + m4) * 2048 + rowb + chunk * 16);
      }
  };
  auto rdB = [&](int d, int nhalf) {        // 4 ds_read_b128
#pragma unroll
    for (int n2 = 0; n2 < 2; ++n2)
#pragma unroll
      for (int kk = 0; kk < 2; ++kk) {
        const int chunk = (qw + kk * 4) ^ rkey;
        b_[n2][kk] = *(const bf16x8*)(sm + d * 65536 + 32768 + (wc >> 1) * 16384 +
                                      (wc & 1) * 8192 + (nhalf * 2 + n2) * 2048 +
                                      rowb + chunk * 16);
      }
  };

  // prologue: d0 full tile0 (8 items), d1.A of tile1 (4 items); wait d0 only.
  stageH(0, 0, 0, 0); stageH(0, 0, 1, 0); stageH(0, 1, 0, 0); stageH(0, 1, 1, 0);
  stageH(1, 0, 0, 1); stageH(1, 0, 1, 1);
  VMW4();
  BAR();

  const int niter = NKT / 2;
  for (int i = 0; i < niter; ++i) {
    const int t0 = 2 * i, t1 = t0 + 1;
    const bool s0 = (t0 + 2 < NKT), s1 = (t1 + 2 < NKT);
    // Ph1: quadrant (0,0) of t0 ; stage d1.B(t1)
    rdA(0, 0); rdB(0, 0);
    stageH(1, 1, 0, t1); stageH(1, 1, 1, t1);
    BAR(); LGKM(); SCHED0(); mfma16<0, 0>(acc, a_, b_); BAR();
    // Ph2: (0,1)
    rdB(0, 1);
    BAR(); LGKM(); SCHED0(); mfma16<0, 1>(acc, a_, b_); BAR();
    // Ph3: (1,1)
    rdA(0, 1);
    BAR(); LGKM(); SCHED0(); mfma16<1, 1>(acc, a_, b_); BAR();
    // Ph4: (1,0) ; stage d0.A(t0+2) ; counted vmcnt
    rdB(0, 0);
    if (s0) { stageH(0, 0, 0, t0 + 2); stageH(0, 0, 1, t0 + 2); }
    BAR(); LGKM(); SCHED0(); mfma16<1, 0>(acc, a_, b_);
    if (s0) { VMW4(); } else { VMW0(); }   // d1 fully landed before ph5
    BAR();
    // Ph5: quadrant (0,0) of t1 ; stage d0.B(t0+2)
    rdA(1, 0); rdB(1, 0);
    if (s0) { stageH(0, 1, 0, t0 + 2); stageH(0, 1, 1, t0 + 2); }
    BAR(); LGKM(); SCHED0(); mfma16<0, 0>(acc, a_, b_); BAR();
    // Ph6: (0,1)
    rdB(1, 1);
    BAR(); LGKM(); SCHED0(); mfma16<0, 1>(acc, a_, b_); BAR();
    // Ph7: (1,1)
    rdA(1, 1);
    BAR(); LGKM(); SCHED0(); mfma16<1, 1>(acc, a_, b_); BAR();
    // Ph8: (1,0) ; stage d1.A(t1+2) ; counted vmcnt
    rdB(1, 0);
    if (s1) { stageH(1, 0, 0, t1 + 2); stageH(1, 0, 1, t1 + 2); }
    BAR(); LGKM(); SCHED0(); mfma16<1, 0>(acc, a_, b_);
    if (s1) { VMW4(); } else if (s0) { VMW0(); }  // d0(t0+2) landed before ph1
    BAR();
  }

  const int e0 = (lane >> 4) * 4;   // C/D: row=(lane>>4)*4+e, col=lane&15

  if constexpr (EPI == 0) {
    const bool diag = (rb == cb);
    float rp[8][4] = {};   // [m][e] row partials
    float rpT[4] = {};     // [n]    col partials
    // mirror image in LDS: uint16 [mr 256][mc 256]; byte = mr*512+mc*2 ^ ((mr&7)<<4)
#pragma unroll
    for (int m = 0; m < 8; ++m) {
      const int growb = row0 + wr * 128 + m * 16 + e0;
#pragma unroll
      for (int n = 0; n < 4; ++n) {
        const int gcol = col0 + wc * 64 + n * 16 + flane;
        ushort4 mpack;
#pragma unroll
        for (int e = 0; e < 4; ++e) {
          const int grow = growb + e;
          const float ev = (grow == gcol) ? 0.0f : __expf(acc[m][n][e]);
          const uint16_t eb = f2bf(ev);
          const float evr = bf2f(eb);     // sum the ROUNDED value (rows sum to 1)
          Eo[(size_t)grow * NR + gcol] = eb;
          rp[m][e] += evr;
          rpT[n] += evr;
          ((uint16_t*)&mpack)[e] = eb;
        }
        if (!diag) {
          const int mr = wc * 64 + n * 16 + flane;     // mirror row (block-local)
          const int mc = wr * 128 + m * 16 + e0;       // mirror col base (4 vals)
          int byte = mr * 512 + mc * 2;
          byte ^= (mr & 7) << 4;                       // 16B-granule XOR, 8B-aligned ok
          *reinterpret_cast<ushort4*>(sm + byte) = mpack;
        }
      }
    }
#pragma unroll
    for (int msk = 1; msk <= 8; msk <<= 1)
#pragma unroll
      for (int m = 0; m < 8; ++m)
#pragma unroll
        for (int e = 0; e < 4; ++e) rp[m][e] += __shfl_xor(rp[m][e], msk, 64);
#pragma unroll
    for (int msk = 16; msk <= 32; msk <<= 1)
#pragma unroll
      for (int n = 0; n < 4; ++n) rpT[n] += __shfl_xor(rpT[n], msk, 64);

    __syncthreads();   // mirror image complete
    if (!diag) {
      // coalesced mirror store: 16 passes x (16 rows x 32 chunks of 16B)
#pragma unroll
      for (int p = 0; p < 16; ++p) {
        const int mr = p * 16 + (tid >> 5);
        const int ch = tid & 31;
        int byte = mr * 512 + ch * 16;
        byte ^= (mr & 7) << 4;
        const u16x8 v = *reinterpret_cast<const u16x8*>(sm + byte);
        *reinterpret_cast<u16x8*>(&Eo[(size_t)(col0 + mr) * NR + row0 + ch * 8]) = v;
      }
    }
    __syncthreads();   // LDS free for partials scratch

    float* sRow = (float*)sm;            // [4][256]
    float* sCol = (float*)(sm + 4096);   // [2][256]
    if (flane == 0) {
#pragma unroll
      for (int m = 0; m < 8; ++m)
#pragma unroll
        for (int e = 0; e < 4; ++e)
          sRow[wc * 256 + wr * 128 + m * 16 + e0 + e] = rp[m][e];
    }
    if (lane < 16) {
#pragma unroll
      for (int n = 0; n < 4; ++n) sCol[wr * 256 + wc * 64 + n * 16 + lane] = rpT[n];
    }
    __syncthreads();
    if (tid < 256) {
      partials[(size_t)cb * NR + row0 + tid] =
          sRow[tid] + sRow[256 + tid] + sRow[512 + tid] + sRow[768 + tid];
      if (!diag)
        partials[(size_t)rb * NR + col0 + tid] = sCol[tid] + sCol[256 + tid];
    }
  } else {
#pragma unroll
    for (int m = 0; m < 8; ++m)
#pragma unroll
      for (int n = 0; n < 4; ++n)
#pragma unroll
        for (int e = 0; e < 4; ++e)
          C[(size_t)(row0 + wr * 128 + m * 16 + e0 + e) * ldc +
            col0 + wc * 64 + n * 16 + flane] = acc[m][n][e];
  }
}

// sims GEMM over upper triangle (rb<=cb), 32x32 tiles of 256, XCD-swizzled
__global__ __launch_bounds__(512, 2) void k_gemm_sym8(
    const uint16_t* __restrict__ Xn, uint16_t* __restrict__ E,
    float* __restrict__ partials) {
  extern __shared__ char smem[];
  const int nwg = gridDim.x;            // 528 = 8*66
  const int cpx = nwg >> 3;
  const int b = blockIdx.x;
  const int swz = (b & 7) * cpx + (b >> 3);
  int rem = swz, rb = 0;
  while (rem >= 32 - rb) { rem -= 32 - rb; ++rb; }
  const int cb = rb + rem;
  gemm8_core<0, 16>(smem, Xn, ND, Xn, ND, rb * 256, cb * 256,
                    nullptr, 0, E, partials, rb, cb);
}

// PV GEMM: out = E(bf16) . X ; split-K x2, fp32 partials
__global__ __launch_bounds__(512, 2) void k_gemm_pv8(
    const uint16_t* __restrict__ E, const uint16_t* __restrict__ XT,
    float* __restrict__ P) {
  extern __shared__ char smem[];
  const int b = blockIdx.x;             // 256 = 8*32
  const int swz = (b & 7) * 32 + (b >> 3);
  const int s = swz >> 7;               // K split
  const int t = swz & 127;
  const int by = t >> 2, bx = t & 3;    // 32 x 4 tiles
  gemm8_core<1, 64>(smem, E + (size_t)s * 4096, NR, XT + (size_t)s * 4096, NR,
                    by * 256, bx * 256, P + (size_t)s * NR * ND, ND,
                    nullptr, nullptr, 0, 0);
}

// ---------------- rowsum: reduce 32 column-block partials ----------------
__global__ void k_rowsum(const float* __restrict__ partials, float* __restrict__ rowsum,
                         int ncb) {
  const int r = blockIdx.x * blockDim.x + threadIdx.x;  // 8192 threads
  float s = 0.0f;
  for (int cb = 0; cb < ncb; ++cb) s += partials[(size_t)cb * NR + r];
  rowsum[r] = s;
}

// ------- fixup: out = (P0 + P1) / rowsum -------
__global__ void k_fixup(const fvec4* __restrict__ P0, const fvec4* __restrict__ P1,
                        const float* __restrict__ rowsum, fvec4* __restrict__ out) {
  const size_t i = (size_t)blockIdx.x * blockDim.x + threadIdx.x;  // float4 units
  const int row = (int)(i >> 8);                                   // /(ND/4)
  const float inv = 1.0f / rowsum[row];
  const fvec4 a = __builtin_nontemporal_load(&P0[i]);
  const fvec4 b = __builtin_nontemporal_load(&P1[i]);
  const fvec4 o = (a + b) * inv;
  __builtin_nontemporal_store(o, &out[i]);
}

// ------- scale: attn(fp32, d_out) = E(bf16) / rowsum -------
__global__ void k_scale(const uint16_t* __restrict__ E, const float* __restrict__ rowsum,
                        float* __restrict__ attn) {
  const size_t total = (size_t)NR * NR / 8;
  for (size_t i = (size_t)blockIdx.x * blockDim.x + threadIdx.x; i < total;
       i += (size_t)gridDim.x * blockDim.x) {
    const int row = (int)(i >> 10);     // (i*8)/8192
    const float inv = 1.0f / rowsum[row];
    const u16x8 e = reinterpret_cast<const u16x8*>(E)[i];   // normal load: E is L3-resident
    fvec4 o0, o1;
    o0.x = bf2f(e[0]) * inv; o0.y = bf2f(e[1]) * inv;
    o0.z = bf2f(e[2]) * inv; o0.w = bf2f(e[3]) * inv;
    o1.x = bf2f(e[4]) * inv; o1.y = bf2f(e[5]) * inv;
    o1.z = bf2f(e[6]) * inv; o1.w = bf2f(e[7]) * inv;
    __builtin_nontemporal_store(o0, &reinterpret_cast<fvec4*>(attn)[2 * i + 0]);
    __builtin_nontemporal_store(o1, &reinterpret_cast<fvec4*>(attn)[2 * i + 1]);
  }
}

extern "C" void kernel_launch(void* const* d_in, const int* in_sizes, int n_in,
                              void* d_out, int out_size, void* d_ws, size_t ws_size,
                              hipStream_t stream) {
  const float* X = (const float*)d_in[0];          // [8192][1024] fp32
  float* out = (float*)d_out;                       // [8192][1024] fp32
  float* attn = out + (size_t)NR * ND;              // [8192][8192] fp32

  char* ws = (char*)d_ws;
  const size_t off_Xn   = 0;                                  // 16 MB bf16 normalized
  const size_t off_XT   = off_Xn + (size_t)NR * ND * 2;       // 16 MB bf16 feats^T
  const size_t off_E    = off_XT + (size_t)ND * NR * 2;       // 128 MB bf16 unscaled exp
  const size_t off_part = off_E + (size_t)NR * NR * 2;        // 2 MB partials
  const size_t off_rs   = off_part + (size_t)64 * NR * 4;     // 32 KB rowsum
  const size_t needed   = off_rs + (size_t)NR * 4;
  if (ws_size < needed) return;

  uint16_t* Xn  = (uint16_t*)(ws + off_Xn);
  uint16_t* XT  = (uint16_t*)(ws + off_XT);
  uint16_t* E   = (uint16_t*)(ws + off_E);
  float* partials = (float*)(ws + off_part);
  float* rowsum   = (float*)(ws + off_rs);

  // PV split-K partials use the (not yet written) attn region of d_out as scratch
  float* P = attn;

  (void)hipFuncSetAttribute((const void*)k_gemm_sym8,
                            hipFuncAttributeMaxDynamicSharedMemorySize, 131072);
  (void)hipFuncSetAttribute((const void*)k_gemm_pv8,
                            hipFuncAttributeMaxDynamicSharedMemorySize, 131072);

  k_norm<<<NR, 256, 0, stream>>>(X, Xn);
  k_transpose<<<(NR / 32) * (ND / 32), 256, 0, stream>>>(X, XT);
  k_gemm_sym8<<<528, 512, 131072, stream>>>(Xn, E, partials);
  k_rowsum<<<NR / 256, 256, 0, stream>>>(partials, rowsum, 32);
  k_gemm_pv8<<<256, 512, 131072, stream>>>(E, XT, P);
  k_fixup<<<NR * ND / 4 / 256, 256, 0, stream>>>(
      (const fvec4*)P, (const fvec4*)(P + (size_t)NR * ND), rowsum, (fvec4*)out);
  k_scale<<<2048, 256, 0, stream>>>(E, rowsum, attn);
}

// Round 11
// 303.625 us; speedup vs baseline: 1.2422x; 1.2422x over previous
//
#include <hip/hip_runtime.h>
#include <hip/hip_bf16.h>
#include <stdint.h>

#define NR 8192   // rows (N)
#define ND 1024   // feature dim (D)

typedef __attribute__((ext_vector_type(8))) short bf16x8;  // 8 bf16 = 4 VGPR
typedef __attribute__((ext_vector_type(4))) float f32x4;   // MFMA C/D
typedef __attribute__((ext_vector_type(4))) float fvec4;   // ext-vector float4 (nontemporal ok)
typedef __attribute__((ext_vector_type(8))) unsigned short u16x8;

static __device__ __forceinline__ uint16_t f2bf(float f) {
  union { __hip_bfloat16 h; uint16_t u; } cv;
  cv.h = __float2bfloat16(f);
  return cv.u;
}
static __device__ __forceinline__ float bf2f(uint16_t u) {
  union { uint32_t i; float f; } cv;
  cv.i = ((uint32_t)u) << 16;
  return cv.f;
}

// ---------------- kernel 1: row L2 norm -> normalized bf16 ----------------
__global__ void k_norm(const float* __restrict__ X, uint16_t* __restrict__ Xn) {
  const int row = blockIdx.x;
  const int t = threadIdx.x;                    // 256 threads, 4 floats each
  const float4 v = reinterpret_cast<const float4*>(X + (size_t)row * ND)[t];
  float ss = v.x * v.x + v.y * v.y + v.z * v.z + v.w * v.w;
#pragma unroll
  for (int m = 1; m < 64; m <<= 1) ss += __shfl_xor(ss, m, 64);
  __shared__ float sred[4];
  if ((t & 63) == 0) sred[t >> 6] = ss;
  __syncthreads();
  const float tot = sred[0] + sred[1] + sred[2] + sred[3];
  const float inv = 1.0f / fmaxf(sqrtf(tot), 1e-12f);
  ushort4 o;
  o.x = f2bf(v.x * inv); o.y = f2bf(v.y * inv);
  o.z = f2bf(v.z * inv); o.w = f2bf(v.w * inv);
  reinterpret_cast<ushort4*>(Xn + (size_t)row * ND)[t] = o;
}

// ------------- kernel 1b: feats [NR][ND] f32 -> featsT [ND][NR] bf16 -------------
__global__ void k_transpose(const float* __restrict__ X, uint16_t* __restrict__ XT) {
  __shared__ uint16_t tile[32][33];
  const int ntr = NR / 32;                     // 256 row-tiles
  const int bx = blockIdx.x % ntr;             // row-tile of X
  const int by = blockIdx.x / ntr;             // col(dim)-tile of X
  const int r0 = bx * 32, d0 = by * 32;
  const int t = threadIdx.x;                   // 256
  const int rr = t >> 3, cc = (t & 7) * 4;
  const float4 v = *reinterpret_cast<const float4*>(&X[(size_t)(r0 + rr) * ND + d0 + cc]);
  tile[cc + 0][rr] = f2bf(v.x);
  tile[cc + 1][rr] = f2bf(v.y);
  tile[cc + 2][rr] = f2bf(v.z);
  tile[cc + 3][rr] = f2bf(v.w);
  __syncthreads();
  ushort4 o;
  o.x = tile[rr][cc + 0]; o.y = tile[rr][cc + 1];
  o.z = tile[rr][cc + 2]; o.w = tile[rr][cc + 3];
  *reinterpret_cast<ushort4*>(&XT[(size_t)(d0 + rr) * NR + r0 + cc]) = o;
}

// ---------------- 16-MFMA quadrant cluster (M-half x N-half x K=64) ----------------
template <int MH, int NH>
static __device__ __forceinline__ void mfma16(f32x4 (&acc)[8][4],
                                              const bf16x8 (&a_)[4][2],
                                              const bf16x8 (&b_)[2][2]) {
  __builtin_amdgcn_s_setprio(1);
#pragma unroll
  for (int kk = 0; kk < 2; ++kk)
#pragma unroll
    for (int m4 = 0; m4 < 4; ++m4)
#pragma unroll
      for (int n2 = 0; n2 < 2; ++n2)
        acc[MH * 4 + m4][NH * 2 + n2] = __builtin_amdgcn_mfma_f32_16x16x32_bf16(
            a_[m4][kk], b_[n2][kk], acc[MH * 4 + m4][NH * 2 + n2], 0, 0, 0);
  __builtin_amdgcn_s_setprio(0);
}

#define BAR()    __builtin_amdgcn_s_barrier()
#define LGKM()   asm volatile("s_waitcnt lgkmcnt(0)" ::: "memory")
#define VMW4()   asm volatile("s_waitcnt vmcnt(4)" ::: "memory")
#define VMW0()   asm volatile("s_waitcnt vmcnt(0)" ::: "memory")
#define SCHED0() __builtin_amdgcn_sched_barrier(0)

// ---------------- 256x256 8-phase BT GEMM core ----------------
// C[m][n] = sum_k A[m][k]*B[n][k]
// LDS map (bytes): dbuf d in {0,1}: d*65536 ; A half h: +h*16384 ; B: +32768+h*16384
// half-tile = [128 rows][64 k] bf16, 128B rows, stored in 16B chunks (8/row).
// Quarter-wave bank swizzle: data chunk c of row r lives at LDS chunk c ^ (r&7);
// stage source col pre-swizzled with the same involution (linear LDS dest).
// A-region addressing (derived from stage geometry, used by emission):
//   lds(d, r in[0,256), c) = d*65536 + (r>>7)*16384 + (r&127)*128 + ((c^(r&7))*16)
// EPI==1 (PV) fuses the attn emission: block emits k-quarter (t>>4)==bx_emit of
// its row-panel: after ph3 (d0) / ph7 (d1), read staged bf16 A-tile from LDS,
// scale by 1/rowsum (hoisted regs), NT-store fp32 to attn. Emission reads drain
// (lgkm + BAR) before ph4/ph8 restage the same region.
template <int EPI, int NKT>
static __device__ __forceinline__ void gemm8_core(
    char* sm,
    const uint16_t* __restrict__ A, int lda,
    const uint16_t* __restrict__ B, int ldb,
    int row0, int col0,
    float* __restrict__ C, int ldc,
    uint16_t* __restrict__ Eo, float* __restrict__ partials, int rb, int cb,
    float* __restrict__ emitA, const float* __restrict__ invrs, int bx_emit) {
  const int tid = threadIdx.x;
  const int wid = tid >> 6;
  const int lane = tid & 63;
  const int wr = wid >> 2;            // 0..1  (M wave)
  const int wc = wid & 3;             // 0..3  (N wave)
  const int flane = lane & 15;
  const int qw = lane >> 4;           // quarter-wave index -> k chunk base
  const int rkey = flane & 7;         // row&7 swizzle key
  const int rowb = flane * 128;

  // staging source geometry (inverse-swizzled global source, linear LDS dest)
  const int colb = (((tid & 7) ^ ((tid >> 3) & 7)) * 16);
  const int r0s = tid >> 3;           // row for load g0; g1 adds 64

  const char* const Abyte = (const char*)A + (size_t)row0 * lda * 2;
  const char* const Bbyte = (const char*)B + (size_t)col0 * ldb * 2;

  f32x4 acc[8][4] = {};
  bf16x8 a_[4][2], b_[2][2];

  // emission row set + hoisted reciprocal rowsums (EPI==1 only)
  float invr0 = 0, invr1 = 0, invr2 = 0, invr3 = 0;
  if constexpr (EPI == 1) {
    const int rb0 = tid >> 3;
    invr0 = invrs[row0 + rb0];
    invr1 = invrs[row0 + 64 + rb0];
    invr2 = invrs[row0 + 128 + rb0];
    invr3 = invrs[row0 + 192 + rb0];
  }

  // one stageH call = 2 global_load_lds instr per wave (one half-tile)
  auto stageH = [&](int d, int isB, int h, int t) {
    const char* gb = isB ? Bbyte : Abyte;
    const int ld2 = (isB ? ldb : lda) * 2;
    const char* g0 = gb + (size_t)(h * 128 + r0s) * ld2 + t * 128 + colb;
    const char* g1 = g0 + (size_t)64 * ld2;
    char* l0 = sm + d * 65536 + isB * 32768 + h * 16384 + (wid << 10);
    __builtin_amdgcn_global_load_lds((const __attribute__((address_space(1))) void*)g0,
                                     (__attribute__((address_space(3))) void*)l0, 16, 0, 0);
    __builtin_amdgcn_global_load_lds((const __attribute__((address_space(1))) void*)g1,
                                     (__attribute__((address_space(3))) void*)(l0 + 8192), 16, 0, 0);
  };
  auto rdA = [&](int d, int mhalf) {        // 8 ds_read_b128
#pragma unroll
    for (int m4 = 0; m4 < 4; ++m4)
#pragma unroll
      for (int kk = 0; kk < 2; ++kk) {
        const int chunk = (qw + kk * 4) ^ rkey;
        a_[m4][kk] = *(const bf16x8*)(sm + d * 65536 + wr * 16384 +
                                      (mhalf * 4 + m4) * 2048 + rowb + chunk * 16);
      }
  };
  auto rdB = [&](int d, int nhalf) {        // 4 ds_read_b128
#pragma unroll
    for (int n2 = 0; n2 < 2; ++n2)
#pragma unroll
      for (int kk = 0; kk < 2; ++kk) {
        const int chunk = (qw + kk * 4) ^ rkey;
        b_[n2][kk] = *(const bf16x8*)(sm + d * 65536 + 32768 + (wc >> 1) * 16384 +
                                      (wc & 1) * 8192 + (nhalf * 2 + n2) * 2048 +
                                      rowb + chunk * 16);
      }
  };
  // emission: scale staged A tile (E bf16) -> fp32 attn. 4 rows/thread, 8 f32x4 stores.
  auto emitT = [&](int d, int t) {
    const int c8 = tid & 7;
    const int rbase = tid >> 3;
#pragma unroll
    for (int p = 0; p < 4; ++p) {
      const int r = p * 64 + rbase;
      const u16x8 ev = *(const u16x8*)(sm + d * 65536 + ((r >> 7) * 16384) +
                                       (r & 127) * 128 + ((c8 ^ (r & 7)) << 4));
      const float inv = (p == 0) ? invr0 : (p == 1) ? invr1 : (p == 2) ? invr2 : invr3;
      fvec4 o0, o1;
      o0.x = bf2f(ev[0]) * inv; o0.y = bf2f(ev[1]) * inv;
      o0.z = bf2f(ev[2]) * inv; o0.w = bf2f(ev[3]) * inv;
      o1.x = bf2f(ev[4]) * inv; o1.y = bf2f(ev[5]) * inv;
      o1.z = bf2f(ev[6]) * inv; o1.w = bf2f(ev[7]) * inv;
      float* dst = emitA + (size_t)(row0 + r) * NR + t * 64 + c8 * 8;
      __builtin_nontemporal_store(o0, (fvec4*)dst);
      __builtin_nontemporal_store(o1, (fvec4*)(dst + 4));
    }
  };

  // prologue: d0 full tile0 (8 items), d1.A of tile1 (4 items); wait d0 only.
  stageH(0, 0, 0, 0); stageH(0, 0, 1, 0); stageH(0, 1, 0, 0); stageH(0, 1, 1, 0);
  stageH(1, 0, 0, 1); stageH(1, 0, 1, 1);
  VMW4();
  BAR();

  const int niter = NKT / 2;
  for (int i = 0; i < niter; ++i) {
    const int t0 = 2 * i, t1 = t0 + 1;
    const bool s0 = (t0 + 2 < NKT), s1 = (t1 + 2 < NKT);
    const bool doEmit = (EPI == 1) && ((t0 >> 4) == bx_emit);
    // Ph1: quadrant (0,0) of t0 ; stage d1.B(t1)
    rdA(0, 0); rdB(0, 0);
    stageH(1, 1, 0, t1); stageH(1, 1, 1, t1);
    BAR(); LGKM(); SCHED0(); mfma16<0, 0>(acc, a_, b_); BAR();
    // Ph2: (0,1)
    rdB(0, 1);
    BAR(); LGKM(); SCHED0(); mfma16<0, 1>(acc, a_, b_); BAR();
    // Ph3: (1,1)
    rdA(0, 1);
    BAR(); LGKM(); SCHED0(); mfma16<1, 1>(acc, a_, b_); BAR();
    // Ph3.5: emit d0's A (E tile t0) before ph4 overwrites it
    if constexpr (EPI == 1) {
      if (doEmit) { emitT(0, t0); LGKM(); BAR(); }
    }
    // Ph4: (1,0) ; stage d0.A(t0+2) ; counted vmcnt
    rdB(0, 0);
    if (s0) { stageH(0, 0, 0, t0 + 2); stageH(0, 0, 1, t0 + 2); }
    BAR(); LGKM(); SCHED0(); mfma16<1, 0>(acc, a_, b_);
    if (s0) { VMW4(); } else { VMW0(); }   // d1 fully landed before ph5
    BAR();
    // Ph5: quadrant (0,0) of t1 ; stage d0.B(t0+2)
    rdA(1, 0); rdB(1, 0);
    if (s0) { stageH(0, 1, 0, t0 + 2); stageH(0, 1, 1, t0 + 2); }
    BAR(); LGKM(); SCHED0(); mfma16<0, 0>(acc, a_, b_); BAR();
    // Ph6: (0,1)
    rdB(1, 1);
    BAR(); LGKM(); SCHED0(); mfma16<0, 1>(acc, a_, b_); BAR();
    // Ph7: (1,1)
    rdA(1, 1);
    BAR(); LGKM(); SCHED0(); mfma16<1, 1>(acc, a_, b_); BAR();
    // Ph7.5: emit d1's A (E tile t1) before ph8 overwrites it
    if constexpr (EPI == 1) {
      if (doEmit) { emitT(1, t1); LGKM(); BAR(); }
    }
    // Ph8: (1,0) ; stage d1.A(t1+2) ; counted vmcnt
    rdB(1, 0);
    if (s1) { stageH(1, 0, 0, t1 + 2); stageH(1, 0, 1, t1 + 2); }
    BAR(); LGKM(); SCHED0(); mfma16<1, 0>(acc, a_, b_);
    if (s1) { VMW4(); } else if (s0) { VMW0(); }  // d0(t0+2) landed before ph1
    BAR();
  }

  const int e0 = (lane >> 4) * 4;   // C/D: row=(lane>>4)*4+e, col=lane&15

  if constexpr (EPI == 0) {
    const bool diag = (rb == cb);
    float rp[8][4] = {};   // [m][e] row partials
    float rpT[4] = {};     // [n]    col partials
    // mirror image in LDS: uint16 [mr 256][mc 256]; byte = mr*512+mc*2 ^ ((mr&7)<<4)
#pragma unroll
    for (int m = 0; m < 8; ++m) {
      const int growb = row0 + wr * 128 + m * 16 + e0;
#pragma unroll
      for (int n = 0; n < 4; ++n) {
        const int gcol = col0 + wc * 64 + n * 16 + flane;
        ushort4 mpack;
#pragma unroll
        for (int e = 0; e < 4; ++e) {
          const int grow = growb + e;
          const float ev = (grow == gcol) ? 0.0f : __expf(acc[m][n][e]);
          const uint16_t eb = f2bf(ev);
          const float evr = bf2f(eb);     // sum the ROUNDED value (rows sum to 1)
          Eo[(size_t)grow * NR + gcol] = eb;
          rp[m][e] += evr;
          rpT[n] += evr;
          ((uint16_t*)&mpack)[e] = eb;
        }
        if (!diag) {
          const int mr = wc * 64 + n * 16 + flane;     // mirror row (block-local)
          const int mc = wr * 128 + m * 16 + e0;       // mirror col base (4 vals)
          int byte = mr * 512 + mc * 2;
          byte ^= (mr & 7) << 4;                       // 16B-granule XOR, 8B-aligned ok
          *reinterpret_cast<ushort4*>(sm + byte) = mpack;
        }
      }
    }
#pragma unroll
    for (int msk = 1; msk <= 8; msk <<= 1)
#pragma unroll
      for (int m = 0; m < 8; ++m)
#pragma unroll
        for (int e = 0; e < 4; ++e) rp[m][e] += __shfl_xor(rp[m][e], msk, 64);
#pragma unroll
    for (int msk = 16; msk <= 32; msk <<= 1)
#pragma unroll
      for (int n = 0; n < 4; ++n) rpT[n] += __shfl_xor(rpT[n], msk, 64);

    __syncthreads();   // mirror image complete
    if (!diag) {
      // coalesced mirror store: 16 passes x (16 rows x 32 chunks of 16B)
#pragma unroll
      for (int p = 0; p < 16; ++p) {
        const int mr = p * 16 + (tid >> 5);
        const int ch = tid & 31;
        int byte = mr * 512 + ch * 16;
        byte ^= (mr & 7) << 4;
        const u16x8 v = *reinterpret_cast<const u16x8*>(sm + byte);
        *reinterpret_cast<u16x8*>(&Eo[(size_t)(col0 + mr) * NR + row0 + ch * 8]) = v;
      }
    }
    __syncthreads();   // LDS free for partials scratch

    float* sRow = (float*)sm;            // [4][256]
    float* sCol = (float*)(sm + 4096);   // [2][256]
    if (flane == 0) {
#pragma unroll
      for (int m = 0; m < 8; ++m)
#pragma unroll
        for (int e = 0; e < 4; ++e)
          sRow[wc * 256 + wr * 128 + m * 16 + e0 + e] = rp[m][e];
    }
    if (lane < 16) {
#pragma unroll
      for (int n = 0; n < 4; ++n) sCol[wr * 256 + wc * 64 + n * 16 + lane] = rpT[n];
    }
    __syncthreads();
    if (tid < 256) {
      partials[(size_t)cb * NR + row0 + tid] =
          sRow[tid] + sRow[256 + tid] + sRow[512 + tid] + sRow[768 + tid];
      if (!diag)
        partials[(size_t)rb * NR + col0 + tid] = sCol[tid] + sCol[256 + tid];
    }
  } else {
#pragma unroll
    for (int m = 0; m < 8; ++m)
#pragma unroll
      for (int n = 0; n < 4; ++n)
#pragma unroll
        for (int e = 0; e < 4; ++e)
          C[(size_t)(row0 + wr * 128 + m * 16 + e0 + e) * ldc +
            col0 + wc * 64 + n * 16 + flane] = acc[m][n][e];
  }
}

// sims GEMM over upper triangle (rb<=cb), 32x32 tiles of 256, XCD-swizzled
__global__ __launch_bounds__(512, 2) void k_gemm_sym8(
    const uint16_t* __restrict__ Xn, uint16_t* __restrict__ E,
    float* __restrict__ partials) {
  extern __shared__ char smem[];
  const int nwg = gridDim.x;            // 528 = 8*66
  const int cpx = nwg >> 3;
  const int b = blockIdx.x;
  const int swz = (b & 7) * cpx + (b >> 3);
  int rem = swz, rb = 0;
  while (rem >= 32 - rb) { rem -= 32 - rb; ++rb; }
  const int cb = rb + rem;
  gemm8_core<0, 16>(smem, Xn, ND, Xn, ND, rb * 256, cb * 256,
                    nullptr, 0, E, partials, rb, cb, nullptr, nullptr, -1);
}

// PV GEMM: P[s] = E_slice(bf16) . XT_slice ; fused attn emission (attn = E/rowsum)
__global__ __launch_bounds__(512, 2) void k_gemm_pv8(
    const uint16_t* __restrict__ E, const uint16_t* __restrict__ XT,
    float* __restrict__ P, float* __restrict__ attn,
    const float* __restrict__ invrs) {
  extern __shared__ char smem[];
  const int b = blockIdx.x;             // 256 = 8*32
  const int swz = (b & 7) * 32 + (b >> 3);
  const int s = swz >> 7;               // K split
  const int t = swz & 127;
  const int by = t >> 2, bx = t & 3;    // 32 x 4 tiles
  gemm8_core<1, 64>(smem, E + (size_t)s * 4096, NR, XT + (size_t)s * 4096, NR,
                    by * 256, bx * 256, P + (size_t)s * NR * ND, ND,
                    nullptr, nullptr, 0, 0,
                    attn + (size_t)s * 4096, invrs, bx);
}

// ------- rowsum: reduce 32 column-block partials, store RECIPROCAL -------
__global__ void k_rowsum(const float* __restrict__ partials, float* __restrict__ rowsum,
                         int ncb) {
  const int r = blockIdx.x * blockDim.x + threadIdx.x;  // 8192 threads
  float s = 0.0f;
  for (int cb = 0; cb < ncb; ++cb) s += partials[(size_t)cb * NR + r];
  rowsum[r] = 1.0f / s;
}

// ------- fixup: out = (P0 + P1) * invrowsum -------
__global__ void k_fixup(const fvec4* __restrict__ P0, const fvec4* __restrict__ P1,
                        const float* __restrict__ rowsum, fvec4* __restrict__ out) {
  const size_t i = (size_t)blockIdx.x * blockDim.x + threadIdx.x;  // float4 units
  const int row = (int)(i >> 8);                                   // /(ND/4)
  const float inv = rowsum[row];
  const fvec4 a = __builtin_nontemporal_load(&P0[i]);
  const fvec4 b = __builtin_nontemporal_load(&P1[i]);
  const fvec4 o = (a + b) * inv;
  __builtin_nontemporal_store(o, &out[i]);
}

extern "C" void kernel_launch(void* const* d_in, const int* in_sizes, int n_in,
                              void* d_out, int out_size, void* d_ws, size_t ws_size,
                              hipStream_t stream) {
  const float* X = (const float*)d_in[0];          // [8192][1024] fp32
  float* out = (float*)d_out;                       // [8192][1024] fp32
  float* attn = out + (size_t)NR * ND;              // [8192][8192] fp32

  char* ws = (char*)d_ws;
  const size_t off_Xn   = 0;                                  // 16 MB bf16 normalized
  const size_t off_XT   = off_Xn + (size_t)NR * ND * 2;       // 16 MB bf16 feats^T
  const size_t off_E    = off_XT + (size_t)ND * NR * 2;       // 128 MB bf16 unscaled exp
  const size_t off_part = off_E + (size_t)NR * NR * 2;        // 2 MB partials
  const size_t off_rs   = off_part + (size_t)64 * NR * 4;     // 32 KB inv-rowsum
  const size_t off_P    = off_rs + (size_t)NR * 4;            // 64 MB PV split-K partials
  const size_t needed   = off_P + (size_t)2 * NR * ND * 4;
  if (ws_size < needed) return;

  uint16_t* Xn  = (uint16_t*)(ws + off_Xn);
  uint16_t* XT  = (uint16_t*)(ws + off_XT);
  uint16_t* E   = (uint16_t*)(ws + off_E);
  float* partials = (float*)(ws + off_part);
  float* rowsum   = (float*)(ws + off_rs);
  float* P        = (float*)(ws + off_P);

  (void)hipFuncSetAttribute((const void*)k_gemm_sym8,
                            hipFuncAttributeMaxDynamicSharedMemorySize, 131072);
  (void)hipFuncSetAttribute((const void*)k_gemm_pv8,
                            hipFuncAttributeMaxDynamicSharedMemorySize, 131072);

  k_norm<<<NR, 256, 0, stream>>>(X, Xn);
  k_transpose<<<(NR / 32) * (ND / 32), 256, 0, stream>>>(X, XT);
  k_gemm_sym8<<<528, 512, 131072, stream>>>(Xn, E, partials);
  k_rowsum<<<NR / 256, 256, 0, stream>>>(partials, rowsum, 32);
  k_gemm_pv8<<<256, 512, 131072, stream>>>(E, XT, P, attn, rowsum);
  k_fixup<<<NR * ND / 4 / 256, 256, 0, stream>>>(
      (const fvec4*)P, (const fvec4*)(P + (size_t)NR * ND), rowsum, (fvec4*)out);
}